// Round 11
// baseline (410.300 us; speedup 1.0000x reference)
//
#include <hip/hip_runtime.h>
#include <hip/hip_bf16.h>
#include <math.h>
#include <stdint.h>

#define B_   4
#define T_   2048
#define D_   1024
#define QH   16
#define KVH  4
#define HD_  64
#define R_   (B_*T_)      // 8192 rows
#define DFF  2048
#define QKVW 1536         // fused q(1024) + kv(512) output width

typedef short short8 __attribute__((ext_vector_type(8)));
typedef short short4v __attribute__((ext_vector_type(4)));
typedef float f32x4 __attribute__((ext_vector_type(4)));

static __device__ __forceinline__ unsigned short f2bu(float x) {
    __hip_bfloat16 h = __float2bfloat16(x);
    return *reinterpret_cast<unsigned short*>(&h);
}

// swizzled byte offset within a 128B/row LDS tile
#define KSWZ(row, cbyte) (((row) << 7) + ((cbyte) ^ (((row) & 7) << 4)))

__device__ __forceinline__ void gload_lds16(const void* g, void* l) {
    typedef __attribute__((address_space(1))) void gv_t;
    typedef __attribute__((address_space(3))) void lv_t;
    __builtin_amdgcn_global_load_lds((gv_t*)g, (lv_t*)l, 16, 0, 0);
}

// ---------------- f32 -> bf16 cast (weights) ----------------
__global__ __launch_bounds__(256) void castw(const float* __restrict__ src,
                                             __hip_bfloat16* __restrict__ dst, int n4) {
    int i = blockIdx.x * 256 + threadIdx.x;
    if (i >= n4) return;
    float4 v = *(const float4*)&src[i*4];
    ushort4 o = { f2bu(v.x), f2bu(v.y), f2bu(v.z), f2bu(v.w) };
    *(ushort4*)&dst[i*4] = o;
}

// ---------------- LayerNorm -> bf16 out: one block per row ----------------
__global__ __launch_bounds__(256) void ln_bf16(const float* __restrict__ x,
                                               const float* __restrict__ g,
                                               const float* __restrict__ bta,
                                               __hip_bfloat16* __restrict__ out) {
    int row = blockIdx.x;
    int tid = threadIdx.x;
    const float* xr = x + (size_t)row * D_;
    int c = tid * 4;
    float4 v = *(const float4*)&xr[c];
    float s = v.x + v.y + v.z + v.w;
#pragma unroll
    for (int off = 32; off >= 1; off >>= 1) s += __shfl_xor(s, off);
    __shared__ float sm[4], sv[4];
    int wid = tid >> 6, lane = tid & 63;
    if (lane == 0) sm[wid] = s;
    __syncthreads();
    float mean = (sm[0] + sm[1] + sm[2] + sm[3]) * (1.0f / D_);
    float d0 = v.x - mean, d1 = v.y - mean, d2 = v.z - mean, d3 = v.w - mean;
    float qq = d0*d0 + d1*d1 + d2*d2 + d3*d3;
#pragma unroll
    for (int off = 32; off >= 1; off >>= 1) qq += __shfl_xor(qq, off);
    if (lane == 0) sv[wid] = qq;
    __syncthreads();
    float var = (sv[0] + sv[1] + sv[2] + sv[3]) * (1.0f / D_);
    float rstd = rsqrtf(var + 1e-5f);
    float4 gg = *(const float4*)&g[c];
    float4 bb = *(const float4*)&bta[c];
    ushort4 o = { f2bu(d0 * rstd * gg.x + bb.x),
                  f2bu(d1 * rstd * gg.y + bb.y),
                  f2bu(d2 * rstd * gg.z + bb.z),
                  f2bu(d3 * rstd * gg.w + bb.w) };
    *(ushort4*)&(out + (size_t)row * D_)[c] = o;
}

// ---------------- bf16 MFMA GEMM: C = res + act(A(MxK) * W(NxK)^T + bias) ----------------
// MODE: 0 plain f32 out; 1 +res f32; 2 +bias,gelu -> bf16; 3 +bias,+res f32
template<int MODE>
__global__ __launch_bounds__(256) void gemm_mfma(const __hip_bfloat16* __restrict__ A,
                                                 const __hip_bfloat16* __restrict__ W,
                                                 const float* __restrict__ bias,
                                                 const float* __restrict__ res,
                                                 float* __restrict__ Cf,
                                                 __hip_bfloat16* __restrict__ Cb,
                                                 int M, int N, int K) {
    __shared__ __hip_bfloat16 At[128*32];
    __shared__ __hip_bfloat16 Bt[128*32];
    int tid = threadIdx.x;
    int w = tid >> 6, lane = tid & 63;
    int l15 = lane & 15, lhi = lane >> 4;
    int bm = blockIdx.y * 128, bn = blockIdx.x * 128;
    int wr = w >> 1, wc = w & 1;
    f32x4 acc[4][4] = {};

    for (int k0 = 0; k0 < K; k0 += 32) {
#pragma unroll
        for (int iss = 0; iss < 2; ++iss) {
            int off = (iss*256 + tid) * 8;     // element offset in 128x32 tile
            int row = off >> 5, col = off & 31;
            gload_lds16(A + (size_t)(bm + row) * K + k0 + col, &At[off]);
            gload_lds16(W + (size_t)(bn + row) * K + k0 + col, &Bt[off]);
        }
        __syncthreads();
        short8 af[4], bf[4];
#pragma unroll
        for (int m = 0; m < 4; ++m) af[m] = *(const short8*)&At[(wr*64 + m*16 + l15)*32 + lhi*8];
#pragma unroll
        for (int n = 0; n < 4; ++n) bf[n] = *(const short8*)&Bt[(wc*64 + n*16 + l15)*32 + lhi*8];
#pragma unroll
        for (int m = 0; m < 4; ++m)
#pragma unroll
            for (int n = 0; n < 4; ++n)
                acc[m][n] = __builtin_amdgcn_mfma_f32_16x16x32_bf16(af[m], bf[n], acc[m][n], 0, 0, 0);
        __syncthreads();
    }

#pragma unroll
    for (int m = 0; m < 4; ++m) {
#pragma unroll
        for (int j = 0; j < 4; ++j) {
            int row = bm + wr*64 + m*16 + lhi*4 + j;
#pragma unroll
            for (int n = 0; n < 4; ++n) {
                int col = bn + wc*64 + n*16 + l15;
                float val = acc[m][n][j];
                if (MODE == 2 || MODE == 3) val += bias[col];
                if (MODE == 2) val = 0.5f * val * (1.0f + erff(val * 0.70710678118654752f));
                if (MODE == 1 || MODE == 3) val += res[(size_t)row * N + col];
                if (MODE == 2) Cb[(size_t)row * N + col] = __float2bfloat16(val);
                else           Cf[(size_t)row * N + col] = val;
            }
        }
    }
}

// ---------------- RoPE + cast q -> qb bf16 [B*QH][T][HD], pre-scaled by log2e/8 (exp2 domain) ----
__global__ __launch_bounds__(256) void rope_cast_q(const float* __restrict__ qkv,
                                                   const float* __restrict__ cosb,
                                                   const float* __restrict__ sinb,
                                                   __hip_bfloat16* __restrict__ qb) {
    const float QS = 0.125f * 1.44269504088896340736f;
    int idx = blockIdx.x * 256 + threadIdx.x;   // total 64*2048*32
    int d2 = idx & 31;
    int t  = (idx >> 5) & (T_ - 1);
    int bh = idx >> 16;          // 0..63
    int b = bh >> 4, h = bh & 15;
    float c0 = cosb[t*HD_ + 2*d2],     s0 = sinb[t*HD_ + 2*d2];
    float c1 = cosb[t*HD_ + 2*d2 + 1], s1 = sinb[t*HD_ + 2*d2 + 1];
    const float* p = qkv + (size_t)(b*T_ + t) * QKVW + h*HD_ + 2*d2;
    float x0 = p[0], x1 = p[1];
    float r0 = (x0*c0 - x1*s0) * QS;
    float r1 = (x1*c1 + x0*s1) * QS;
    __hip_bfloat16* qo = qb + ((size_t)bh * T_ + t) * HD_ + 2*d2;
    qo[0] = __float2bfloat16(r0);
    qo[1] = __float2bfloat16(r1);
}

// ---------------- RoPE+cast k -> kb [B*KVH][T][HD]; v -> vbt [B*KVH][HD][T] ----------------
__global__ __launch_bounds__(256) void rope_cast_kv(const float* __restrict__ qkv,
                                                    const float* __restrict__ cosb,
                                                    const float* __restrict__ sinb,
                                                    __hip_bfloat16* __restrict__ kb,
                                                    __hip_bfloat16* __restrict__ vbt) {
    int idx = blockIdx.x * 256 + threadIdx.x;   // total 16*2048*32
    int d2 = idx & 31;
    int t  = (idx >> 5) & (T_ - 1);
    int bk = idx >> 16;          // 0..15
    int b = bk >> 2, kh = bk & 3;
    float c0 = cosb[t*HD_ + 2*d2],     s0 = sinb[t*HD_ + 2*d2];
    float c1 = cosb[t*HD_ + 2*d2 + 1], s1 = sinb[t*HD_ + 2*d2 + 1];
    const float* p = qkv + (size_t)(b*T_ + t) * QKVW + 1024 + kh*(2*HD_) + 2*d2;
    float k0 = p[0], k1 = p[1];
    float v0 = p[HD_], v1 = p[HD_ + 1];
    float r0 = k0*c0 - k1*s0;
    float r1 = k1*c1 + k0*s1;
    __hip_bfloat16* ko = kb + ((size_t)bk * T_ + t) * HD_ + 2*d2;
    ko[0] = __float2bfloat16(r0);
    ko[1] = __float2bfloat16(r1);
    vbt[((size_t)bk * HD_ + 2*d2    ) * T_ + t] = __float2bfloat16(v0);
    vbt[((size_t)bk * HD_ + 2*d2 + 1) * T_ + t] = __float2bfloat16(v1);
}

// ---------------- Flash attention: QBLK=128 (4 waves x 32 q-rows), swapped operands ----------------
// QK^T as mfma(K,Q): lane holds S[key=cb*16+lhi*4+r][qrow] for its 2 q-rows (qh=0,1).
// PV as mfma(V^T,P): lane holds O^T[d=cb*16+lhi*4+r][qrow].
// K/V staged via global_load_lds with pre-swizzled SOURCE (linear LDS dest); reads use KSWZ.
// Softmax in exp2 domain (Q pre-scaled by log2e/8).
__global__ __launch_bounds__(256) void attn_mfma(const __hip_bfloat16* __restrict__ qb,
                                                 const __hip_bfloat16* __restrict__ kb,
                                                 const __hip_bfloat16* __restrict__ vbt,
                                                 __hip_bfloat16* __restrict__ ob) {
    __shared__ __hip_bfloat16 Ks[64*64];    // [key][d]   8KB swizzled
    __shared__ __hip_bfloat16 Vs[64*64];    // [d][key]   8KB swizzled
    __shared__ __hip_bfloat16 Ps[128*64];   // [qrow][key] 16KB swizzled, per-wave rows
    char* KsB = (char*)Ks; char* VsB = (char*)Vs; char* PsB = (char*)Ps;
    int tid = threadIdx.x;
    int w = tid >> 6, lane = tid & 63;
    int l15 = lane & 15, lhi = lane >> 4;
    int bh = blockIdx.y;
    int b = bh >> 4, h = bh & 15;
    int bk = b * KVH + (h >> 2);
    int qt0 = blockIdx.x * 128;

    // Q fragments for the wave's two 16-row halves
    short8 qf[2][2];
#pragma unroll
    for (int qh = 0; qh < 2; ++qh) {
        const __hip_bfloat16* qrow = qb + ((size_t)bh * T_ + qt0 + w*32 + qh*16 + l15) * HD_;
        qf[qh][0] = *(const short8*)(qrow + lhi*8);
        qf[qh][1] = *(const short8*)(qrow + 32 + lhi*8);
    }

    f32x4 oacc[2][4] = {};
    float m_run[2] = {-INFINITY, -INFINITY};
    float l_run[2] = {0.f, 0.f};

    const __hip_bfloat16* kbase = kb  + (size_t)bk * T_ * HD_;
    const __hip_bfloat16* vbase = vbt + (size_t)bk * HD_ * T_;
    // pre-swizzled source addressing for gload_lds (linear LDS dest = chunk + lane*16)
    int lrow = lane >> 3;                         // row within 8-row chunk
    int scol = ((lane & 7) * 16) ^ (lrow << 4);   // swizzled source col (bytes)
    int sce  = scol >> 1;                         // elements

    for (int s0 = 0; s0 < T_; s0 += 64) {
#pragma unroll
        for (int c = 0; c < 2; ++c) {
            int rw = (w + 4*c) * 8 + lrow;        // tile row 0..63 (rw&7 == lrow)
            int ldsoff = (w + 4*c) * 1024 + lane * 16;
            gload_lds16(kbase + (size_t)(s0 + rw) * HD_ + sce, KsB + ldsoff);
            gload_lds16(vbase + (size_t)rw * T_ + s0 + sce,    VsB + ldsoff);
        }
        __syncthreads();

        // S^T = K Q^T for both q-halves (K-frags reused)
        f32x4 accs[2][4];
#pragma unroll
        for (int cb = 0; cb < 4; ++cb) {
            short8 k0 = *(const short8*)(KsB + KSWZ(cb*16 + l15, lhi*16));
            short8 k1 = *(const short8*)(KsB + KSWZ(cb*16 + l15, 64 + lhi*16));
            __builtin_amdgcn_s_setprio(1);
#pragma unroll
            for (int qh = 0; qh < 2; ++qh) {
                f32x4 z = {0.f, 0.f, 0.f, 0.f};
                z = __builtin_amdgcn_mfma_f32_16x16x32_bf16(k0, qf[qh][0], z, 0, 0, 0);
                z = __builtin_amdgcn_mfma_f32_16x16x32_bf16(k1, qf[qh][1], z, 0, 0, 0);
                accs[qh][cb] = z;
            }
            __builtin_amdgcn_s_setprio(0);
        }

        // online softmax (exp2 domain), per q-half
#pragma unroll
        for (int qh = 0; qh < 2; ++qh) {
            float mx = -INFINITY;
#pragma unroll
            for (int cb = 0; cb < 4; ++cb)
#pragma unroll
                for (int r = 0; r < 4; ++r) mx = fmaxf(mx, accs[qh][cb][r]);
            mx = fmaxf(mx, __shfl_xor(mx, 16));
            mx = fmaxf(mx, __shfl_xor(mx, 32));
            float mn = fmaxf(m_run[qh], mx);
            float cr = exp2f(m_run[qh] - mn);
            m_run[qh] = mn;
            float rs = 0.0f;
            int pr = w*32 + qh*16 + l15;
#pragma unroll
            for (int cb = 0; cb < 4; ++cb) {
                f32x4 p;
#pragma unroll
                for (int r = 0; r < 4; ++r) { p[r] = exp2f(accs[qh][cb][r] - mn); rs += p[r]; }
                short4v pk = { (short)f2bu(p[0]), (short)f2bu(p[1]),
                               (short)f2bu(p[2]), (short)f2bu(p[3]) };
                *(short4v*)(PsB + KSWZ(pr, cb*32 + lhi*8)) = pk;
            }
            rs += __shfl_xor(rs, 16);
            rs += __shfl_xor(rs, 32);
            l_run[qh] = l_run[qh] * cr + rs;
#pragma unroll
            for (int cb = 0; cb < 4; ++cb)
#pragma unroll
                for (int r = 0; r < 4; ++r) oacc[qh][cb][r] *= cr;
        }
        // no barrier: P write->read is same-wave (lgkmcnt-ordered)

        // O^T += V^T P^T (V-frags reused across q-halves)
#pragma unroll
        for (int kk = 0; kk < 2; ++kk) {
            short8 pf0 = *(const short8*)(PsB + KSWZ(w*32 + l15,      kk*64 + lhi*16));
            short8 pf1 = *(const short8*)(PsB + KSWZ(w*32 + 16 + l15, kk*64 + lhi*16));
            __builtin_amdgcn_s_setprio(1);
#pragma unroll
            for (int cb = 0; cb < 4; ++cb) {
                short8 vf = *(const short8*)(VsB + KSWZ(cb*16 + l15, kk*64 + lhi*16));
                oacc[0][cb] = __builtin_amdgcn_mfma_f32_16x16x32_bf16(vf, pf0, oacc[0][cb], 0, 0, 0);
                oacc[1][cb] = __builtin_amdgcn_mfma_f32_16x16x32_bf16(vf, pf1, oacc[1][cb], 0, 0, 0);
            }
            __builtin_amdgcn_s_setprio(0);
        }
        __syncthreads();   // all waves done with Ks/Vs before restage
    }

#pragma unroll
    for (int qh = 0; qh < 2; ++qh) {
        float inv = 1.0f / l_run[qh];
        int t = qt0 + w*32 + qh*16 + l15;
        __hip_bfloat16* orow = ob + (size_t)(b*T_ + t) * D_ + h*HD_;
#pragma unroll
        for (int cb = 0; cb < 4; ++cb) {
            short4v okv = { (short)f2bu(oacc[qh][cb][0] * inv), (short)f2bu(oacc[qh][cb][1] * inv),
                            (short)f2bu(oacc[qh][cb][2] * inv), (short)f2bu(oacc[qh][cb][3] * inv) };
            *(short4v*)&orow[cb*16 + lhi*4] = okv;
        }
    }
}

extern "C" void kernel_launch(void* const* d_in, const int* in_sizes, int n_in,
                              void* d_out, int out_size, void* d_ws, size_t ws_size,
                              hipStream_t stream) {
    const float* x    = (const float*)d_in[0];
    const float* cosb = (const float*)d_in[1];
    const float* sinb = (const float*)d_in[2];
    const float* Wq   = (const float*)d_in[3];
    const float* Wkv  = (const float*)d_in[4];
    const float* Wo   = (const float*)d_in[5];
    const float* ln1g = (const float*)d_in[6];
    const float* ln1b = (const float*)d_in[7];
    const float* ln2g = (const float*)d_in[8];
    const float* ln2b = (const float*)d_in[9];
    const float* W1   = (const float*)d_in[10];
    const float* b1   = (const float*)d_in[11];
    const float* W2   = (const float*)d_in[12];
    const float* b2   = (const float*)d_in[13];
    float* out = (float*)d_out;

    float* ws = (float*)d_ws;
    const size_t M = 1024 * 1024;
    __hip_bfloat16* hb   = (__hip_bfloat16*)(ws);
    float*          x2   = ws + 4*M;
    float*          qkv  = ws + 12*M;
    __hip_bfloat16* gbuf = (__hip_bfloat16*)(ws + 12*M);
    __hip_bfloat16* ob   = (__hip_bfloat16*)(ws + 20*M);
    __hip_bfloat16* qb   = (__hip_bfloat16*)(ws + 24*M);
    __hip_bfloat16* kbb  = (__hip_bfloat16*)(ws + 28*M);
    __hip_bfloat16* vbt  = (__hip_bfloat16*)(ws + 29*M);
    __hip_bfloat16* Wqkvb= (__hip_bfloat16*)(ws + 30*M);
    __hip_bfloat16* Wob  = (__hip_bfloat16*)(ws + 30*M + 3*M/4);
    __hip_bfloat16* W1b  = (__hip_bfloat16*)(ws + 31*M + M/4);
    __hip_bfloat16* W2b  = (__hip_bfloat16*)(ws + 32*M + M/4);

    // 0. weight casts (bf16)
    castw<<<(1024*1024/4 + 255)/256, 256, 0, stream>>>(Wq,  Wqkvb,              1024*1024/4);
    castw<<<( 512*1024/4 + 255)/256, 256, 0, stream>>>(Wkv, Wqkvb + 1024*1024,   512*1024/4);
    castw<<<(1024*1024/4 + 255)/256, 256, 0, stream>>>(Wo,  Wob,               1024*1024/4);
    castw<<<(2048*1024/4 + 255)/256, 256, 0, stream>>>(W1,  W1b,               2048*1024/4);
    castw<<<(2048*1024/4 + 255)/256, 256, 0, stream>>>(W2,  W2b,               2048*1024/4);

    // 1. LN1 -> hb (bf16)
    ln_bf16<<<R_, 256, 0, stream>>>(x, ln1g, ln1b, hb);
    // 2. qkv = hb @ Wqkvb^T (f32 out)
    gemm_mfma<0><<<dim3(QKVW/128, R_/128), 256, 0, stream>>>(hb, Wqkvb, nullptr, nullptr, qkv, nullptr, R_, QKVW, D_);
    // 3. RoPE + bf16 cast (q in exp2 domain)
    rope_cast_q <<<(R_*QH*32)/256,  256, 0, stream>>>(qkv, cosb, sinb, qb);
    rope_cast_kv<<<(R_*KVH*32)/256, 256, 0, stream>>>(qkv, cosb, sinb, kbb, vbt);
    // 4. attention -> ob (bf16)
    attn_mfma<<<dim3(T_/128, B_*QH), 256, 0, stream>>>(qb, kbb, vbt, ob);
    // 5. x2 = x + ob @ Wob^T
    gemm_mfma<1><<<dim3(D_/128, R_/128), 256, 0, stream>>>(ob, Wob, nullptr, x, x2, nullptr, R_, D_, D_);
    // 6. LN2 -> hb (bf16)
    ln_bf16<<<R_, 256, 0, stream>>>(x2, ln2g, ln2b, hb);
    // 7. gbuf = gelu(hb @ W1b^T + b1) (bf16 out)
    gemm_mfma<2><<<dim3(DFF/128, R_/128), 256, 0, stream>>>(hb, W1b, b1, nullptr, nullptr, gbuf, R_, DFF, D_);
    // 8. out = x2 + gbuf @ W2b^T + b2
    gemm_mfma<3><<<dim3(D_/128, R_/128), 256, 0, stream>>>(gbuf, W2b, b2, x2, out, nullptr, R_, D_, DFF);
}